// Round 2
// baseline (1249.062 us; speedup 1.0000x reference)
//
#include <hip/hip_runtime.h>
#include <hip/hip_bf16.h>
#include <cstdint>
#include <cstddef>

using bf16 = __bf16;
typedef __bf16 bf16x8 __attribute__((ext_vector_type(8)));
typedef __bf16 bf16x4 __attribute__((ext_vector_type(4)));
typedef float  f32x4  __attribute__((ext_vector_type(4)));

#define DEV __device__ __forceinline__

DEV float sigmoidf_(float x) { return 1.0f / (1.0f + __expf(-x)); }

typedef __attribute__((address_space(1))) void as1_void;
typedef __attribute__((address_space(3))) void as3_void;

// async global->LDS, 16B per lane; LDS dest = wave-uniform base + lane*16
DEV void load16_lds(const void* g, void* l) {
  __builtin_amdgcn_global_load_lds((as1_void*)(void*)g, (as3_void*)l, 16, 0, 0);
}

// ---------------- kernel 1: rmsnorm -> x (bf16) ----------------
__global__ __launch_bounds__(256) void k_rms_x(const float* __restrict__ inp,
                                               const float* __restrict__ nw,
                                               bf16* __restrict__ x) {
  const int row = blockIdx.x;            // b*S + s
  const int t = threadIdx.x;
  const float* r = inp + (size_t)row * 1024 + t * 4;
  f32x4 v = *(const f32x4*)r;
  float ss = v[0]*v[0] + v[1]*v[1] + v[2]*v[2] + v[3]*v[3];
  __shared__ float red[4];
  for (int off = 32; off; off >>= 1) ss += __shfl_down(ss, off);
  if ((t & 63) == 0) red[t >> 6] = ss;
  __syncthreads();
  float tot = red[0] + red[1] + red[2] + red[3];
  float sc = rsqrtf(tot * (1.0f / 1024.0f) + 1e-5f);
  f32x4 w = *(const f32x4*)(nw + t * 4);
  bf16x4 o;
  o[0] = (bf16)(v[0] * sc * w[0]); o[1] = (bf16)(v[1] * sc * w[1]);
  o[2] = (bf16)(v[2] * sc * w[2]); o[3] = (bf16)(v[3] * sc * w[3]);
  *(bf16x4*)(x + (size_t)row * 1024 + t * 4) = o;
}

// ---------------- kernel 2: column partial sums of x ----------------
__global__ __launch_bounds__(256) void k_colsum(const bf16* __restrict__ x,
                                                float* __restrict__ part) {
  const int b = blockIdx.y, c = blockIdx.x;   // 32 chunks x 128 rows
  const int d = threadIdx.x * 4;
  f32x4 s = {0.f, 0.f, 0.f, 0.f};
  const bf16* base = x + ((size_t)b * 4096 + (size_t)c * 128) * 1024 + d;
  for (int i = 0; i < 128; ++i) {
    bf16x4 v = *(const bf16x4*)(base + (size_t)i * 1024);
    s[0] += (float)v[0]; s[1] += (float)v[1];
    s[2] += (float)v[2]; s[3] += (float)v[3];
  }
  *(f32x4*)(part + ((size_t)(b * 32 + c)) * 1024 + d) = s;
}

// ---------------- kernel 3: router logits -> softmax probs (1 block/batch) ----------------
__global__ __launch_bounds__(256) void k_router(const float* __restrict__ part,
                                                const float* __restrict__ rw,
                                                const float* __restrict__ rb,
                                                float* __restrict__ probs,
                                                float* __restrict__ aux) {
  const int b = blockIdx.x;
  const int t = threadIdx.x;
  __shared__ float red[4];
  __shared__ float lg[3];
  f32x4 cs = {0.f, 0.f, 0.f, 0.f};
  #pragma unroll 8
  for (int c = 0; c < 32; ++c)
    cs += *(const f32x4*)(part + ((size_t)(b * 32 + c)) * 1024 + t * 4);
  for (int e = 0; e < 3; ++e) {
    float dot = cs[0] * rw[(t*4+0)*3+e] + cs[1] * rw[(t*4+1)*3+e]
              + cs[2] * rw[(t*4+2)*3+e] + cs[3] * rw[(t*4+3)*3+e];
    for (int off = 32; off; off >>= 1) dot += __shfl_down(dot, off);
    if ((t & 63) == 0) red[t >> 6] = dot;
    __syncthreads();
    if (t == 0) lg[e] = (red[0]+red[1]+red[2]+red[3]) * (1.0f/4096.0f) + rb[e];
    __syncthreads();
  }
  if (t == 0) {
    float m = fmaxf(lg[0], fmaxf(lg[1], lg[2]));
    float p0 = __expf(lg[0]-m), p1 = __expf(lg[1]-m), p2 = __expf(lg[2]-m);
    float inv = 1.0f / (p0 + p1 + p2);
    probs[b*3+0] = p0*inv; probs[b*3+1] = p1*inv; probs[b*3+2] = p2*inv;
    if (b == 0) *aux = 0.0f;
  }
}

// ------- kernel 4: mix experts by probs + transpose -> [B][N][K] bf16 -------
__global__ __launch_bounds__(256) void k_mixT(const float* __restrict__ W,  // [3][1024][Ncols]
                                              const float* __restrict__ probs,
                                              bf16* __restrict__ out,       // [8][Ncols][1024]
                                              int Ncols) {
  const int b = blockIdx.z;
  const int i0 = blockIdx.y * 64;   // K dim (1024)
  const int j0 = blockIdx.x * 64;   // N dim (Ncols)
  const float p0 = probs[b*3+0], p1 = probs[b*3+1], p2 = probs[b*3+2];
  __shared__ float tile[64][68];
  const int t = threadIdx.x;
  const int jl = (t & 15) * 4;
  const size_t estr = (size_t)1024 * Ncols;
  for (int ii = 0; ii < 4; ++ii) {
    int il = (t >> 4) + ii * 16;
    const float* src = W + (size_t)(i0 + il) * Ncols + (j0 + jl);
    f32x4 v0 = *(const f32x4*)(src);
    f32x4 v1 = *(const f32x4*)(src + estr);
    f32x4 v2 = *(const f32x4*)(src + 2 * estr);
    f32x4 v = p0 * v0 + p1 * v1 + p2 * v2;
    tile[il][jl+0] = v[0]; tile[il][jl+1] = v[1];
    tile[il][jl+2] = v[2]; tile[il][jl+3] = v[3];
  }
  __syncthreads();
  bf16* ob = out + (size_t)b * Ncols * 1024;
  const int il2 = (t & 15) * 4;
  for (int jj = 0; jj < 4; ++jj) {
    int jl2 = (t >> 4) + jj * 16;
    bf16x4 o;
    o[0] = (bf16)tile[il2+0][jl2]; o[1] = (bf16)tile[il2+1][jl2];
    o[2] = (bf16)tile[il2+2][jl2]; o[3] = (bf16)tile[il2+3][jl2];
    *(bf16x4*)(ob + (size_t)(j0 + jl2) * 1024 + (i0 + il2)) = o;
  }
}

// ================= 256x256 GEMM, safe double-buffer schedule =================
// C[M,N] = A[M,K] @ Bt[N,K]^T, bf16 MFMA 16x16x32. BM=BN=256, BK=64, 8 waves
// (2M x 4N), 512 threads, 128 KiB LDS (2 bufs x {A,B} x 256x64 bf16).
// Schedule (airtight; no hand vmcnt): per K-tile t, issue all 8 half-tile
// global_load_lds for t+1 into nbuf, compute tile t's 4 quadrants (64 MFMA)
// from buf as plain code, then one __syncthreads() (compiler drains
// vmcnt(0)+lgkmcnt(0) before s_barrier -> t+1 visible, buf reads retired).
// Stages touch ONLY nbuf; reads ONLY buf -> no mid-tile overwrite hazards.
// LDS granule swizzle: row r granule g stored at g ^ (r&7) (16B granules).
// EPI 0: B rows permuted so hid (nq=0) and gate (nq=1) of the SAME j are
//        in-thread: hid=acc[mi][ni], gate=acc[mi][ni+2]. Writes bf16 a,b.
// EPI 1: LDS-retiled coalesced f32x4 epilogue with fp32 addend.
template<int EPI>
__global__ __launch_bounds__(512, 1) void k_gemm256(const bf16* __restrict__ A,
                                                    const bf16* __restrict__ Bt,
                                                    const float* __restrict__ addend,
                                                    float* __restrict__ Cout,
                                                    bf16* __restrict__ pa,
                                                    bf16* __restrict__ pb,
                                                    int M, int N, int K) {
  const int bz = blockIdx.z;
  // bijective XCD swizzle within the z-slice (nwg % 8 == 0 at both call sites)
  const int nx = gridDim.x;
  const int nwg = nx * gridDim.y;
  const int orig = blockIdx.y * nx + blockIdx.x;
  const int swz = (orig & 7) * (nwg >> 3) + (orig >> 3);
  const int tm = swz / nx, tn = swz % nx;

  __shared__ __align__(16) char smem[131072];
  const int tid = threadIdx.x;
  const int lane = tid & 63, w = tid >> 6;
  const int l15 = lane & 15, quad = lane >> 4;
  const int wm = (w >> 2) * 128;        // wave M-half base in tile
  const int wn = (w & 3) * 64;          // wave N-quarter base in tile

  const bf16* Ab  = A  + (size_t)bz * M * K;
  const bf16* Btb = Bt + (size_t)bz * N * K;

  // staging: granule q = i*512 + tid; local row = q>>3 (0..127); source granule
  // kc = (q&7) ^ (row&7) so LDS slot (row, s) holds source granule s^(row&7).
  const int row0 = tid >> 3,          kc0 = (tid & 7) ^ (row0 & 7);
  const int row1 = (512 + tid) >> 3,  kc1 = (tid & 7) ^ (row1 & 7);

  auto browf = [&](int c) -> int {
    if constexpr (EPI == 0) {
      // tile col c -> WgT row: j = tn*128 + (c>>6)*32 + (c&31); gate iff (c&63)>=32
      return tn * 128 + ((c >> 6) * 32) + (c & 31) + (((c & 63) >= 32) ? 1024 : 0);
    } else {
      return tn * 256 + c;
    }
  };
  const bf16* aS0_0 = Ab + (size_t)(tm*256 +       row0) * K + kc0 * 8;
  const bf16* aS0_1 = Ab + (size_t)(tm*256 +       row1) * K + kc1 * 8;
  const bf16* aS1_0 = Ab + (size_t)(tm*256 + 128 + row0) * K + kc0 * 8;
  const bf16* aS1_1 = Ab + (size_t)(tm*256 + 128 + row1) * K + kc1 * 8;
  const bf16* bS0_0 = Btb + (size_t)browf(row0)       * K + kc0 * 8;
  const bf16* bS0_1 = Btb + (size_t)browf(row1)       * K + kc1 * 8;
  const bf16* bS1_0 = Btb + (size_t)browf(128 + row0) * K + kc0 * 8;
  const bf16* bS1_1 = Btb + (size_t)browf(128 + row1) * K + kc1 * 8;

  const int ld0 = tid * 16;          // i=0 LDS byte offset within half-tile
  const int ld1 = 8192 + tid * 16;   // i=1
  // LDS map: A buf at buf*32768 (+16384 for half1); B at 65536 + same
  auto stage = [&](int buf, int u) {
    load16_lds(aS0_0 + u*64, smem + buf*32768 + ld0);
    load16_lds(aS0_1 + u*64, smem + buf*32768 + ld1);
    load16_lds(aS1_0 + u*64, smem + buf*32768 + 16384 + ld0);
    load16_lds(aS1_1 + u*64, smem + buf*32768 + 16384 + ld1);
    load16_lds(bS0_0 + u*64, smem + 65536 + buf*32768 + ld0);
    load16_lds(bS0_1 + u*64, smem + 65536 + buf*32768 + ld1);
    load16_lds(bS1_0 + u*64, smem + 65536 + buf*32768 + 16384 + ld0);
    load16_lds(bS1_1 + u*64, smem + 65536 + buf*32768 + 16384 + ld1);
  };

  f32x4 acc[8][4] = {};
  bf16x8 a[4][2], b0[2][2], b1[2][2];

  auto ldA = [&](int buf, int mq) {
    const bf16* base = (const bf16*)(smem + buf*32768);
    #pragma unroll
    for (int mi = 0; mi < 4; ++mi) {
      const int m = wm + mq*64 + mi*16 + l15;
      #pragma unroll
      for (int ks = 0; ks < 2; ++ks) {
        const int kc = ks*4 + quad;
        a[mi][ks] = *(const bf16x8*)(base + (size_t)(m*8 + (kc ^ (m & 7))) * 8);
      }
    }
  };
  auto ldB = [&](int buf, int nq, bf16x8 (&bb)[2][2]) {
    const bf16* base = (const bf16*)(smem + 65536 + buf*32768);
    #pragma unroll
    for (int ni = 0; ni < 2; ++ni) {
      const int n = wn + nq*32 + ni*16 + l15;
      #pragma unroll
      for (int ks = 0; ks < 2; ++ks) {
        const int kc = ks*4 + quad;
        bb[ni][ks] = *(const bf16x8*)(base + (size_t)(n*8 + (kc ^ (n & 7))) * 8);
      }
    }
  };

#define MMAC(MQ, NQ, BB)                                                        \
  _Pragma("unroll")                                                             \
  for (int mi = 0; mi < 4; ++mi) {                                              \
    _Pragma("unroll")                                                           \
    for (int ni = 0; ni < 2; ++ni) {                                            \
      f32x4 c_ = acc[(MQ)*4 + mi][(NQ)*2 + ni];                                 \
      c_ = __builtin_amdgcn_mfma_f32_16x16x32_bf16(a[mi][0], BB[ni][0], c_, 0, 0, 0); \
      c_ = __builtin_amdgcn_mfma_f32_16x16x32_bf16(a[mi][1], BB[ni][1], c_, 0, 0, 0); \
      acc[(MQ)*4 + mi][(NQ)*2 + ni] = c_;                                       \
    }                                                                           \
  }

  const int NT = K >> 6;   // K-tiles (16)

  stage(0, 0);
  __syncthreads();         // compiler drains vmcnt(0) before barrier: tile 0 ready

  for (int t = 0; t < NT; ++t) {
    const int buf = t & 1;
    if (t + 1 < NT) stage(buf ^ 1, t + 1);   // 8 loads in flight over the MFMAs
    // quadrants (0,0) (0,1) (1,1) (1,0); b0 and b1 carried in registers
    ldA(buf, 0);
    ldB(buf, 0, b0);
    MMAC(0, 0, b0);
    ldB(buf, 1, b1);
    MMAC(0, 1, b1);
    ldA(buf, 1);
    MMAC(1, 1, b1);
    MMAC(1, 0, b0);
    __syncthreads();       // drain vmcnt(0)+lgkmcnt(0): t+1 staged, buf reads done
  }

  if constexpr (EPI == 0) {
    // fused activation; in-thread pairing: hid = acc[mi][ni], gate = acc[mi][ni+2]
    bf16* Aab = pa + (size_t)bz * M * 1024;
    bf16* Bab = pb + (size_t)bz * M * 1024;
    const int jb = tn * 128 + (w & 3) * 32;
    const int rb = tm * 256 + wm;
    #pragma unroll
    for (int mi = 0; mi < 8; ++mi)
      #pragma unroll
      for (int ni = 0; ni < 2; ++ni)
        #pragma unroll
        for (int r = 0; r < 4; ++r) {
          const int srow = rb + mi * 16 + quad * 4 + r;
          float hid = acc[mi][ni][r];
          float gt  = acc[mi][ni + 2][r];
          float z = sigmoidf_(gt);
          float av = 1.0f - z;
          float gv = (hid >= 0.0f) ? (hid + 0.5f) : sigmoidf_(hid);
          float bv = z * gv;
          size_t oidx = (size_t)srow * 1024 + jb + ni * 16 + l15;
          Aab[oidx] = (bf16)av;
          Bab[oidx] = (bf16)bv;
        }
  } else {
    // LDS-retiled coalesced epilogue: 8 passes of 32 rows; ST=260 keeps 16B align
    float* sC = (float*)smem;
    const int ST = 260;
    float* C = Cout + (size_t)bz * M * N;
    const float* Ain = addend + (size_t)bz * M * N;
    #pragma unroll 1
    for (int p = 0; p < 8; ++p) {
      if ((w >> 2) == (p >> 2)) {
        const int mi0 = (p & 3) * 2;
        #pragma unroll
        for (int mm = 0; mm < 2; ++mm)
          #pragma unroll
          for (int nt_ = 0; nt_ < 4; ++nt_)
            #pragma unroll
            for (int r = 0; r < 4; ++r) {
              const int rl = mm * 16 + quad * 4 + r;
              sC[rl * ST + (w & 3) * 64 + nt_ * 16 + l15] = acc[mi0 + mm][nt_][r];
            }
      }
      __syncthreads();
      #pragma unroll
      for (int i = 0; i < 4; ++i) {
        const int v = i * 512 + tid;
        const int rl = v >> 6, c4 = (v & 63) * 4;
        const int grow = tm * 256 + p * 32 + rl;
        const int gcol = tn * 256 + c4;
        f32x4 cv = *(f32x4*)(sC + rl * ST + c4);
        f32x4 ad = *(const f32x4*)(Ain + (size_t)grow * N + gcol);
        *(f32x4*)(C + (size_t)grow * N + gcol) = cv + ad;
      }
      __syncthreads();
    }
  }
#undef MMAC
}

// pass 1: per-chunk (prodA, scanB) summaries. chunks of 64 steps.
__global__ __launch_bounds__(256) void k_scan1(const bf16* __restrict__ Aab,
                                               const bf16* __restrict__ Bab,
                                               float* __restrict__ cA,
                                               float* __restrict__ cB) {
  const int b = blockIdx.y, c = blockIdx.x;
  const int d = threadIdx.x * 4;
  f32x4 A = {1.f, 1.f, 1.f, 1.f}, Bv = {0.f, 0.f, 0.f, 0.f};
  const size_t base = ((size_t)(b * 4096 + c * 64)) * 1024 + d;
  #pragma unroll 4
  for (int i = 0; i < 64; ++i) {
    bf16x4 av = *(const bf16x4*)(Aab + base + (size_t)i * 1024);
    bf16x4 bv = *(const bf16x4*)(Bab + base + (size_t)i * 1024);
    #pragma unroll
    for (int j = 0; j < 4; ++j) {
      float a = (float)av[j], bb = (float)bv[j];
      A[j] *= a; Bv[j] = a * Bv[j] + bb;
    }
  }
  *(f32x4*)(cA + ((size_t)(b * 64 + c)) * 1024 + d) = A;
  *(f32x4*)(cB + ((size_t)(b * 64 + c)) * 1024 + d) = Bv;
}

// pass 2: chunk-level prefix; writes per-chunk entry state + new_state
__global__ __launch_bounds__(256) void k_scan2(const float* __restrict__ cA,
                                               const float* __restrict__ cB,
                                               const float* __restrict__ state,
                                               float* __restrict__ hin,
                                               float* __restrict__ ns) {
  const int gid = blockIdx.x * 256 + threadIdx.x;  // 8192 channels
  const int b = gid >> 10, d = gid & 1023;
  float h = state[gid];
  for (int c0 = 0; c0 < 64; c0 += 8) {
    float ar[8], br[8];
    #pragma unroll
    for (int i = 0; i < 8; ++i) {
      size_t idx = (((size_t)(b * 64 + c0 + i)) << 10) + d;
      ar[i] = cA[idx]; br[i] = cB[idx];
    }
    #pragma unroll
    for (int i = 0; i < 8; ++i) {
      size_t idx = (((size_t)(b * 64 + c0 + i)) << 10) + d;
      hin[idx] = h;
      h = ar[i] * h + br[i];
    }
  }
  ns[gid] = h;
}

// pass 3: replay chunk with known entry state, write h (bf16)
__global__ __launch_bounds__(256) void k_scan3(const bf16* __restrict__ Aab,
                                               const bf16* __restrict__ Bab,
                                               const float* __restrict__ hin,
                                               bf16* __restrict__ hq) {
  const int b = blockIdx.y, c = blockIdx.x;
  const int d = threadIdx.x * 4;
  f32x4 h = *(const f32x4*)(hin + ((size_t)(b * 64 + c)) * 1024 + d);
  const size_t base = ((size_t)(b * 4096 + c * 64)) * 1024 + d;
  bf16* ob = hq + base;
  #pragma unroll 4
  for (int i = 0; i < 64; ++i) {
    bf16x4 av = *(const bf16x4*)(Aab + base + (size_t)i * 1024);
    bf16x4 bv = *(const bf16x4*)(Bab + base + (size_t)i * 1024);
    bf16x4 o;
    #pragma unroll
    for (int j = 0; j < 4; ++j) {
      h[j] = (float)av[j] * h[j] + (float)bv[j];
      o[j] = (bf16)h[j];
    }
    *(bf16x4*)(ob + (size_t)i * 1024) = o;
  }
}

extern "C" void kernel_launch(void* const* d_in, const int* in_sizes, int n_in,
                              void* d_out, int out_size, void* d_ws, size_t ws_size,
                              hipStream_t stream) {
  const float* inputs   = (const float*)d_in[0];
  const float* state    = (const float*)d_in[1];
  const float* norm_w   = (const float*)d_in[2];
  const float* router_w = (const float*)d_in[3];
  const float* router_b = (const float*)d_in[4];
  const float* w_gh     = (const float*)d_in[5];
  const float* w_out    = (const float*)d_in[6];

  float* out = (float*)d_out;
  float* new_state = out + (size_t)8 * 4096 * 1024;
  float* aux = new_state + 8 * 1024;

  char* ws = (char*)d_ws;
  size_t off = 0;
  auto alloc = [&](size_t bytes) {
    char* p = ws + off;
    off = (off + bytes + 255) & ~(size_t)255;
    return p;
  };
  bf16*  x    = (bf16*)alloc((size_t)8 * 4096 * 1024 * 2);   // 64 MB
  bf16*  a_ar = (bf16*)alloc((size_t)8 * 4096 * 1024 * 2);   // 64 MB
  bf16*  b_ar = (bf16*)alloc((size_t)8 * 4096 * 1024 * 2);   // 64 MB
  bf16*  hq   = (bf16*)alloc((size_t)8 * 4096 * 1024 * 2);   // 64 MB
  bf16*  WgT  = (bf16*)alloc((size_t)8 * 2048 * 1024 * 2);   // 32 MB
  bf16*  WoT  = (bf16*)alloc((size_t)8 * 1024 * 1024 * 2);   // 16 MB
  float* part = (float*)alloc((size_t)8 * 32 * 1024 * 4);    // 1 MB
  float* probs = (float*)alloc(256);
  float* cA   = (float*)alloc((size_t)8 * 64 * 1024 * 4);    // 2 MB
  float* cB   = (float*)alloc((size_t)8 * 64 * 1024 * 4);
  float* hin  = (float*)alloc((size_t)8 * 64 * 1024 * 4);
  (void)in_sizes; (void)n_in; (void)out_size; (void)ws_size;

  k_rms_x <<<32768, 256, 0, stream>>>(inputs, norm_w, x);
  k_colsum<<<dim3(32, 8), 256, 0, stream>>>(x, part);
  k_router<<<8, 256, 0, stream>>>(part, router_w, router_b, probs, aux);
  k_mixT  <<<dim3(32, 16, 8), 256, 0, stream>>>(w_gh, probs, WgT, 2048);
  k_mixT  <<<dim3(16, 16, 8), 256, 0, stream>>>(w_out, probs, WoT, 1024);
  k_gemm256<0><<<dim3(8, 16, 8), 512, 0, stream>>>(x, WgT, nullptr, nullptr,
                                                   a_ar, b_ar, 4096, 2048, 1024);
  k_scan1 <<<dim3(64, 8), 256, 0, stream>>>(a_ar, b_ar, cA, cB);
  k_scan2 <<<32, 256, 0, stream>>>(cA, cB, state, hin, new_state);
  k_scan3 <<<dim3(64, 8), 256, 0, stream>>>(a_ar, b_ar, hin, hq);
  k_gemm256<1><<<dim3(4, 16, 8), 512, 0, stream>>>(hq, WoT, inputs, out,
                                                   nullptr, nullptr, 4096, 1024, 1024);
}

// Round 3
// 580.101 us; speedup vs baseline: 2.1532x; 2.1532x over previous
//
#include <hip/hip_runtime.h>
#include <hip/hip_bf16.h>
#include <cstdint>
#include <cstddef>

using bf16 = __bf16;
typedef __bf16 bf16x8 __attribute__((ext_vector_type(8)));
typedef __bf16 bf16x4 __attribute__((ext_vector_type(4)));
typedef float  f32x4  __attribute__((ext_vector_type(4)));

#define DEV __device__ __forceinline__

DEV float sigmoidf_(float x) { return 1.0f / (1.0f + __expf(-x)); }

typedef __attribute__((address_space(1))) void as1_void;
typedef __attribute__((address_space(3))) void as3_void;

// async global->LDS, 16B per lane; LDS dest = wave-uniform base + lane*16
DEV void load16_lds(const void* g, void* l) {
  __builtin_amdgcn_global_load_lds((as1_void*)(void*)g, (as3_void*)l, 16, 0, 0);
}

// ---------------- kernel 1: rmsnorm -> x (bf16) ----------------
__global__ __launch_bounds__(256) void k_rms_x(const float* __restrict__ inp,
                                               const float* __restrict__ nw,
                                               bf16* __restrict__ x) {
  const int row = blockIdx.x;            // b*S + s
  const int t = threadIdx.x;
  const float* r = inp + (size_t)row * 1024 + t * 4;
  f32x4 v = *(const f32x4*)r;
  float ss = v[0]*v[0] + v[1]*v[1] + v[2]*v[2] + v[3]*v[3];
  __shared__ float red[4];
  for (int off = 32; off; off >>= 1) ss += __shfl_down(ss, off);
  if ((t & 63) == 0) red[t >> 6] = ss;
  __syncthreads();
  float tot = red[0] + red[1] + red[2] + red[3];
  float sc = rsqrtf(tot * (1.0f / 1024.0f) + 1e-5f);
  f32x4 w = *(const f32x4*)(nw + t * 4);
  bf16x4 o;
  o[0] = (bf16)(v[0] * sc * w[0]); o[1] = (bf16)(v[1] * sc * w[1]);
  o[2] = (bf16)(v[2] * sc * w[2]); o[3] = (bf16)(v[3] * sc * w[3]);
  *(bf16x4*)(x + (size_t)row * 1024 + t * 4) = o;
}

// ---------------- kernel 2: column partial sums of x ----------------
__global__ __launch_bounds__(256) void k_colsum(const bf16* __restrict__ x,
                                                float* __restrict__ part) {
  const int b = blockIdx.y, c = blockIdx.x;   // 32 chunks x 128 rows
  const int d = threadIdx.x * 4;
  f32x4 s = {0.f, 0.f, 0.f, 0.f};
  const bf16* base = x + ((size_t)b * 4096 + (size_t)c * 128) * 1024 + d;
  for (int i = 0; i < 128; ++i) {
    bf16x4 v = *(const bf16x4*)(base + (size_t)i * 1024);
    s[0] += (float)v[0]; s[1] += (float)v[1];
    s[2] += (float)v[2]; s[3] += (float)v[3];
  }
  *(f32x4*)(part + ((size_t)(b * 32 + c)) * 1024 + d) = s;
}

// ---------------- kernel 3: router logits -> softmax probs (1 block/batch) ----------------
__global__ __launch_bounds__(256) void k_router(const float* __restrict__ part,
                                                const float* __restrict__ rw,
                                                const float* __restrict__ rb,
                                                float* __restrict__ probs,
                                                float* __restrict__ aux) {
  const int b = blockIdx.x;
  const int t = threadIdx.x;
  __shared__ float red[4];
  __shared__ float lg[3];
  f32x4 cs = {0.f, 0.f, 0.f, 0.f};
  #pragma unroll 8
  for (int c = 0; c < 32; ++c)
    cs += *(const f32x4*)(part + ((size_t)(b * 32 + c)) * 1024 + t * 4);
  for (int e = 0; e < 3; ++e) {
    float dot = cs[0] * rw[(t*4+0)*3+e] + cs[1] * rw[(t*4+1)*3+e]
              + cs[2] * rw[(t*4+2)*3+e] + cs[3] * rw[(t*4+3)*3+e];
    for (int off = 32; off; off >>= 1) dot += __shfl_down(dot, off);
    if ((t & 63) == 0) red[t >> 6] = dot;
    __syncthreads();
    if (t == 0) lg[e] = (red[0]+red[1]+red[2]+red[3]) * (1.0f/4096.0f) + rb[e];
    __syncthreads();
  }
  if (t == 0) {
    float m = fmaxf(lg[0], fmaxf(lg[1], lg[2]));
    float p0 = __expf(lg[0]-m), p1 = __expf(lg[1]-m), p2 = __expf(lg[2]-m);
    float inv = 1.0f / (p0 + p1 + p2);
    probs[b*3+0] = p0*inv; probs[b*3+1] = p1*inv; probs[b*3+2] = p2*inv;
    if (b == 0) *aux = 0.0f;
  }
}

// ------- kernel 4: mix experts by probs + transpose -> [B][N][K] bf16 -------
__global__ __launch_bounds__(256) void k_mixT(const float* __restrict__ W,  // [3][1024][Ncols]
                                              const float* __restrict__ probs,
                                              bf16* __restrict__ out,       // [8][Ncols][1024]
                                              int Ncols) {
  const int b = blockIdx.z;
  const int i0 = blockIdx.y * 64;   // K dim (1024)
  const int j0 = blockIdx.x * 64;   // N dim (Ncols)
  const float p0 = probs[b*3+0], p1 = probs[b*3+1], p2 = probs[b*3+2];
  __shared__ float tile[64][68];
  const int t = threadIdx.x;
  const int jl = (t & 15) * 4;
  const size_t estr = (size_t)1024 * Ncols;
  for (int ii = 0; ii < 4; ++ii) {
    int il = (t >> 4) + ii * 16;
    const float* src = W + (size_t)(i0 + il) * Ncols + (j0 + jl);
    f32x4 v0 = *(const f32x4*)(src);
    f32x4 v1 = *(const f32x4*)(src + estr);
    f32x4 v2 = *(const f32x4*)(src + 2 * estr);
    f32x4 v = p0 * v0 + p1 * v1 + p2 * v2;
    tile[il][jl+0] = v[0]; tile[il][jl+1] = v[1];
    tile[il][jl+2] = v[2]; tile[il][jl+3] = v[3];
  }
  __syncthreads();
  bf16* ob = out + (size_t)b * Ncols * 1024;
  const int il2 = (t & 15) * 4;
  for (int jj = 0; jj < 4; ++jj) {
    int jl2 = (t >> 4) + jj * 16;
    bf16x4 o;
    o[0] = (bf16)tile[il2+0][jl2]; o[1] = (bf16)tile[il2+1][jl2];
    o[2] = (bf16)tile[il2+2][jl2]; o[3] = (bf16)tile[il2+3][jl2];
    *(bf16x4*)(ob + (size_t)(j0 + jl2) * 1024 + (i0 + il2)) = o;
  }
}

// ================= 256x256 GEMM, safe double-buffer schedule =================
// C[M,N] = A[M,K] @ Bt[N,K]^T, bf16 MFMA 16x16x32. BM=BN=256, BK=64, 8 waves
// (2M x 4N), 512 threads, 128 KiB LDS (2 bufs x {A,B} x 256x64 bf16).
// Schedule: per K-tile t, issue all 8 half-tile global_load_lds for t+1 into
// nbuf, compute tile t's 4 quadrants (64 MFMA) from buf, then one
// __syncthreads() (drains vmcnt+lgkmcnt -> t+1 visible, buf reads retired).
// LDS granule swizzle: row r granule g stored at g ^ (r&7) (16B granules).
// RULE #20: every acc[] index must be compile-time constant (runtime index
// sent acc to scratch in R2 -> 2.25 GiB write traffic, 768 us). All epilogue
// loops are fully unrolled.
// EPI 0: B rows permuted so hid (nq=0) and gate (nq=1) of the SAME j are
//        in-thread: hid=acc[mi][ni], gate=acc[mi][ni+2]. Writes bf16 a,b.
// EPI 1: LDS-retiled coalesced f32x4 epilogue with fp32 addend.
template<int EPI>
__global__ __launch_bounds__(512, 1) void k_gemm256(const bf16* __restrict__ A,
                                                    const bf16* __restrict__ Bt,
                                                    const float* __restrict__ addend,
                                                    float* __restrict__ Cout,
                                                    bf16* __restrict__ pa,
                                                    bf16* __restrict__ pb,
                                                    int M, int N, int K) {
  const int bz = blockIdx.z;
  // bijective XCD swizzle within the z-slice (nwg % 8 == 0 at both call sites)
  const int nx = gridDim.x;
  const int nwg = nx * gridDim.y;
  const int orig = blockIdx.y * nx + blockIdx.x;
  const int swz = (orig & 7) * (nwg >> 3) + (orig >> 3);
  const int tm = swz / nx, tn = swz % nx;

  __shared__ __align__(16) char smem[131072];
  const int tid = threadIdx.x;
  const int lane = tid & 63, w = tid >> 6;
  const int l15 = lane & 15, quad = lane >> 4;
  const int wm = (w >> 2) * 128;        // wave M-half base in tile
  const int wn = (w & 3) * 64;          // wave N-quarter base in tile

  const bf16* Ab  = A  + (size_t)bz * M * K;
  const bf16* Btb = Bt + (size_t)bz * N * K;

  // staging: granule q = i*512 + tid; local row = q>>3 (0..127); source granule
  // kc = (q&7) ^ (row&7) so LDS slot (row, s) holds source granule s^(row&7).
  const int row0 = tid >> 3,          kc0 = (tid & 7) ^ (row0 & 7);
  const int row1 = (512 + tid) >> 3,  kc1 = (tid & 7) ^ (row1 & 7);

  auto browf = [&](int c) -> int {
    if constexpr (EPI == 0) {
      // tile col c -> WgT row: j = tn*128 + (c>>6)*32 + (c&31); gate iff (c&63)>=32
      return tn * 128 + ((c >> 6) * 32) + (c & 31) + (((c & 63) >= 32) ? 1024 : 0);
    } else {
      return tn * 256 + c;
    }
  };
  const bf16* aS0_0 = Ab + (size_t)(tm*256 +       row0) * K + kc0 * 8;
  const bf16* aS0_1 = Ab + (size_t)(tm*256 +       row1) * K + kc1 * 8;
  const bf16* aS1_0 = Ab + (size_t)(tm*256 + 128 + row0) * K + kc0 * 8;
  const bf16* aS1_1 = Ab + (size_t)(tm*256 + 128 + row1) * K + kc1 * 8;
  const bf16* bS0_0 = Btb + (size_t)browf(row0)       * K + kc0 * 8;
  const bf16* bS0_1 = Btb + (size_t)browf(row1)       * K + kc1 * 8;
  const bf16* bS1_0 = Btb + (size_t)browf(128 + row0) * K + kc0 * 8;
  const bf16* bS1_1 = Btb + (size_t)browf(128 + row1) * K + kc1 * 8;

  const int ld0 = tid * 16;          // i=0 LDS byte offset within half-tile
  const int ld1 = 8192 + tid * 16;   // i=1
  // LDS map: A buf at buf*32768 (+16384 for half1); B at 65536 + same
  auto stage = [&](int buf, int u) {
    load16_lds(aS0_0 + u*64, smem + buf*32768 + ld0);
    load16_lds(aS0_1 + u*64, smem + buf*32768 + ld1);
    load16_lds(aS1_0 + u*64, smem + buf*32768 + 16384 + ld0);
    load16_lds(aS1_1 + u*64, smem + buf*32768 + 16384 + ld1);
    load16_lds(bS0_0 + u*64, smem + 65536 + buf*32768 + ld0);
    load16_lds(bS0_1 + u*64, smem + 65536 + buf*32768 + ld1);
    load16_lds(bS1_0 + u*64, smem + 65536 + buf*32768 + 16384 + ld0);
    load16_lds(bS1_1 + u*64, smem + 65536 + buf*32768 + 16384 + ld1);
  };

  f32x4 acc[8][4] = {};
  bf16x8 a[4][2], b0[2][2], b1[2][2];

  auto ldA = [&](int buf, int mq) {
    const bf16* base = (const bf16*)(smem + buf*32768);
    #pragma unroll
    for (int mi = 0; mi < 4; ++mi) {
      const int m = wm + mq*64 + mi*16 + l15;
      #pragma unroll
      for (int ks = 0; ks < 2; ++ks) {
        const int kc = ks*4 + quad;
        a[mi][ks] = *(const bf16x8*)(base + (size_t)(m*8 + (kc ^ (m & 7))) * 8);
      }
    }
  };
  auto ldB = [&](int buf, int nq, bf16x8 (&bb)[2][2]) {
    const bf16* base = (const bf16*)(smem + 65536 + buf*32768);
    #pragma unroll
    for (int ni = 0; ni < 2; ++ni) {
      const int n = wn + nq*32 + ni*16 + l15;
      #pragma unroll
      for (int ks = 0; ks < 2; ++ks) {
        const int kc = ks*4 + quad;
        bb[ni][ks] = *(const bf16x8*)(base + (size_t)(n*8 + (kc ^ (n & 7))) * 8);
      }
    }
  };

#define MMAC(MQ, NQ, BB)                                                        \
  _Pragma("unroll")                                                             \
  for (int mi = 0; mi < 4; ++mi) {                                              \
    _Pragma("unroll")                                                           \
    for (int ni = 0; ni < 2; ++ni) {                                            \
      f32x4 c_ = acc[(MQ)*4 + mi][(NQ)*2 + ni];                                 \
      c_ = __builtin_amdgcn_mfma_f32_16x16x32_bf16(a[mi][0], BB[ni][0], c_, 0, 0, 0); \
      c_ = __builtin_amdgcn_mfma_f32_16x16x32_bf16(a[mi][1], BB[ni][1], c_, 0, 0, 0); \
      acc[(MQ)*4 + mi][(NQ)*2 + ni] = c_;                                       \
    }                                                                           \
  }

  const int NT = K >> 6;   // K-tiles (16)

  stage(0, 0);
  __syncthreads();         // compiler drains vmcnt(0) before barrier: tile 0 ready

  for (int t = 0; t < NT; ++t) {
    const int buf = t & 1;
    if (t + 1 < NT) stage(buf ^ 1, t + 1);   // 8 loads in flight over the MFMAs
    // quadrants (0,0) (0,1) (1,1) (1,0); b0 and b1 carried in registers
    ldA(buf, 0);
    ldB(buf, 0, b0);
    MMAC(0, 0, b0);
    ldB(buf, 1, b1);
    MMAC(0, 1, b1);
    ldA(buf, 1);
    MMAC(1, 1, b1);
    MMAC(1, 0, b0);
    __syncthreads();       // drain vmcnt(0)+lgkmcnt(0): t+1 staged, buf reads done
  }

  if constexpr (EPI == 0) {
    // fused activation; in-thread pairing: hid = acc[mi][ni], gate = acc[mi][ni+2]
    bf16* Aab = pa + (size_t)bz * M * 1024;
    bf16* Bab = pb + (size_t)bz * M * 1024;
    const int jb = tn * 128 + (w & 3) * 32;
    const int rb = tm * 256 + wm;
    #pragma unroll
    for (int mi = 0; mi < 8; ++mi)
      #pragma unroll
      for (int ni = 0; ni < 2; ++ni)
        #pragma unroll
        for (int r = 0; r < 4; ++r) {
          const int srow = rb + mi * 16 + quad * 4 + r;
          float hid = acc[mi][ni][r];
          float gt  = acc[mi][ni + 2][r];
          float z = sigmoidf_(gt);
          float av = 1.0f - z;
          float gv = (hid >= 0.0f) ? (hid + 0.5f) : sigmoidf_(hid);
          float bv = z * gv;
          size_t oidx = (size_t)srow * 1024 + jb + ni * 16 + l15;
          Aab[oidx] = (bf16)av;
          Bab[oidx] = (bf16)bv;
        }
  } else {
    // LDS-retiled coalesced epilogue: 8 passes of 32 rows; ST=260 keeps 16B align.
    // FULLY UNROLLED (p compile-time) so every acc[] index is static (rule #20).
    float* sC = (float*)smem;
    const int ST = 260;
    float* C = Cout + (size_t)bz * M * N;
    const float* Ain = addend + (size_t)bz * M * N;
    #pragma unroll
    for (int p = 0; p < 8; ++p) {
      if ((w >> 2) == (p >> 2)) {
        const int mi0 = (p & 3) * 2;
        #pragma unroll
        for (int mm = 0; mm < 2; ++mm)
          #pragma unroll
          for (int nt_ = 0; nt_ < 4; ++nt_)
            #pragma unroll
            for (int r = 0; r < 4; ++r) {
              const int rl = mm * 16 + quad * 4 + r;
              sC[rl * ST + (w & 3) * 64 + nt_ * 16 + l15] = acc[mi0 + mm][nt_][r];
            }
      }
      __syncthreads();
      #pragma unroll
      for (int i = 0; i < 4; ++i) {
        const int v = i * 512 + tid;
        const int rl = v >> 6, c4 = (v & 63) * 4;
        const int grow = tm * 256 + p * 32 + rl;
        const int gcol = tn * 256 + c4;
        f32x4 cv = *(f32x4*)(sC + rl * ST + c4);
        f32x4 ad = *(const f32x4*)(Ain + (size_t)grow * N + gcol);
        *(f32x4*)(C + (size_t)grow * N + gcol) = cv + ad;
      }
      __syncthreads();
    }
  }
#undef MMAC
}

// pass 1: per-chunk (prodA, scanB) summaries. chunks of 64 steps.
__global__ __launch_bounds__(256) void k_scan1(const bf16* __restrict__ Aab,
                                               const bf16* __restrict__ Bab,
                                               float* __restrict__ cA,
                                               float* __restrict__ cB) {
  const int b = blockIdx.y, c = blockIdx.x;
  const int d = threadIdx.x * 4;
  f32x4 A = {1.f, 1.f, 1.f, 1.f}, Bv = {0.f, 0.f, 0.f, 0.f};
  const size_t base = ((size_t)(b * 4096 + c * 64)) * 1024 + d;
  #pragma unroll 4
  for (int i = 0; i < 64; ++i) {
    bf16x4 av = *(const bf16x4*)(Aab + base + (size_t)i * 1024);
    bf16x4 bv = *(const bf16x4*)(Bab + base + (size_t)i * 1024);
    #pragma unroll
    for (int j = 0; j < 4; ++j) {
      float a = (float)av[j], bb = (float)bv[j];
      A[j] *= a; Bv[j] = a * Bv[j] + bb;
    }
  }
  *(f32x4*)(cA + ((size_t)(b * 64 + c)) * 1024 + d) = A;
  *(f32x4*)(cB + ((size_t)(b * 64 + c)) * 1024 + d) = Bv;
}

// pass 2: chunk-level prefix; writes per-chunk entry state + new_state
__global__ __launch_bounds__(256) void k_scan2(const float* __restrict__ cA,
                                               const float* __restrict__ cB,
                                               const float* __restrict__ state,
                                               float* __restrict__ hin,
                                               float* __restrict__ ns) {
  const int gid = blockIdx.x * 256 + threadIdx.x;  // 8192 channels
  const int b = gid >> 10, d = gid & 1023;
  float h = state[gid];
  for (int c0 = 0; c0 < 64; c0 += 8) {
    float ar[8], br[8];
    #pragma unroll
    for (int i = 0; i < 8; ++i) {
      size_t idx = (((size_t)(b * 64 + c0 + i)) << 10) + d;
      ar[i] = cA[idx]; br[i] = cB[idx];
    }
    #pragma unroll
    for (int i = 0; i < 8; ++i) {
      size_t idx = (((size_t)(b * 64 + c0 + i)) << 10) + d;
      hin[idx] = h;
      h = ar[i] * h + br[i];
    }
  }
  ns[gid] = h;
}

// pass 3: replay chunk with known entry state, write h (bf16)
__global__ __launch_bounds__(256) void k_scan3(const bf16* __restrict__ Aab,
                                               const bf16* __restrict__ Bab,
                                               const float* __restrict__ hin,
                                               bf16* __restrict__ hq) {
  const int b = blockIdx.y, c = blockIdx.x;
  const int d = threadIdx.x * 4;
  f32x4 h = *(const f32x4*)(hin + ((size_t)(b * 64 + c)) * 1024 + d);
  const size_t base = ((size_t)(b * 4096 + c * 64)) * 1024 + d;
  bf16* ob = hq + base;
  #pragma unroll 4
  for (int i = 0; i < 64; ++i) {
    bf16x4 av = *(const bf16x4*)(Aab + base + (size_t)i * 1024);
    bf16x4 bv = *(const bf16x4*)(Bab + base + (size_t)i * 1024);
    bf16x4 o;
    #pragma unroll
    for (int j = 0; j < 4; ++j) {
      h[j] = (float)av[j] * h[j] + (float)bv[j];
      o[j] = (bf16)h[j];
    }
    *(bf16x4*)(ob + (size_t)i * 1024) = o;
  }
}

extern "C" void kernel_launch(void* const* d_in, const int* in_sizes, int n_in,
                              void* d_out, int out_size, void* d_ws, size_t ws_size,
                              hipStream_t stream) {
  const float* inputs   = (const float*)d_in[0];
  const float* state    = (const float*)d_in[1];
  const float* norm_w   = (const float*)d_in[2];
  const float* router_w = (const float*)d_in[3];
  const float* router_b = (const float*)d_in[4];
  const float* w_gh     = (const float*)d_in[5];
  const float* w_out    = (const float*)d_in[6];

  float* out = (float*)d_out;
  float* new_state = out + (size_t)8 * 4096 * 1024;
  float* aux = new_state + 8 * 1024;

  char* ws = (char*)d_ws;
  size_t off = 0;
  auto alloc = [&](size_t bytes) {
    char* p = ws + off;
    off = (off + bytes + 255) & ~(size_t)255;
    return p;
  };
  bf16*  x    = (bf16*)alloc((size_t)8 * 4096 * 1024 * 2);   // 64 MB
  bf16*  a_ar = (bf16*)alloc((size_t)8 * 4096 * 1024 * 2);   // 64 MB
  bf16*  b_ar = (bf16*)alloc((size_t)8 * 4096 * 1024 * 2);   // 64 MB
  bf16*  hq   = (bf16*)alloc((size_t)8 * 4096 * 1024 * 2);   // 64 MB
  bf16*  WgT  = (bf16*)alloc((size_t)8 * 2048 * 1024 * 2);   // 32 MB
  bf16*  WoT  = (bf16*)alloc((size_t)8 * 1024 * 1024 * 2);   // 16 MB
  float* part = (float*)alloc((size_t)8 * 32 * 1024 * 4);    // 1 MB
  float* probs = (float*)alloc(256);
  float* cA   = (float*)alloc((size_t)8 * 64 * 1024 * 4);    // 2 MB
  float* cB   = (float*)alloc((size_t)8 * 64 * 1024 * 4);
  float* hin  = (float*)alloc((size_t)8 * 64 * 1024 * 4);
  (void)in_sizes; (void)n_in; (void)out_size; (void)ws_size;

  k_rms_x <<<32768, 256, 0, stream>>>(inputs, norm_w, x);
  k_colsum<<<dim3(32, 8), 256, 0, stream>>>(x, part);
  k_router<<<8, 256, 0, stream>>>(part, router_w, router_b, probs, aux);
  k_mixT  <<<dim3(32, 16, 8), 256, 0, stream>>>(w_gh, probs, WgT, 2048);
  k_mixT  <<<dim3(16, 16, 8), 256, 0, stream>>>(w_out, probs, WoT, 1024);
  k_gemm256<0><<<dim3(8, 16, 8), 512, 0, stream>>>(x, WgT, nullptr, nullptr,
                                                   a_ar, b_ar, 4096, 2048, 1024);
  k_scan1 <<<dim3(64, 8), 256, 0, stream>>>(a_ar, b_ar, cA, cB);
  k_scan2 <<<32, 256, 0, stream>>>(cA, cB, state, hin, new_state);
  k_scan3 <<<dim3(64, 8), 256, 0, stream>>>(a_ar, b_ar, hin, hq);
  k_gemm256<1><<<dim3(4, 16, 8), 512, 0, stream>>>(hq, WoT, inputs, out,
                                                   nullptr, nullptr, 4096, 1024, 1024);
}